// Round 8
// baseline (1047.522 us; speedup 1.0000x reference)
//
#include <hip/hip_runtime.h>
#include <math.h>

#define DIM 1024
#define P0 512
#define H 16
#define HD 64
#define B 2
#define S 1024
#define PT 1536   // P0 + S

typedef __attribute__((ext_vector_type(8))) short short8v;    // bf16 MFMA frag
typedef __attribute__((ext_vector_type(4))) float f32x4;
typedef __attribute__((ext_vector_type(8))) unsigned short ushort8v;
typedef __attribute__((ext_vector_type(4))) unsigned short ushort4v;

__device__ __forceinline__ unsigned short bf16_rne(float x) {
  unsigned u = __builtin_bit_cast(unsigned, x);
  u += 0x7FFFu + ((u >> 16) & 1u);
  return (unsigned short)(u >> 16);
}
__device__ __forceinline__ float bf16_f(unsigned short h) {
  unsigned u = ((unsigned)h) << 16;
  return __builtin_bit_cast(float, u);
}

// ---------------------------------------------------------------- mag ----
__global__ __launch_bounds__(256) void k_mag(const float* __restrict__ zr,
                                             const float* __restrict__ zi,
                                             float* __restrict__ mag, int n4) {
  int i = blockIdx.x * blockDim.x + threadIdx.x;
  if (i < n4) {
    float4 a = ((const float4*)zr)[i];
    float4 b = ((const float4*)zi)[i];
    float4 o;
    o.x = sqrtf(a.x * a.x + b.x * b.x);
    o.y = sqrtf(a.y * a.y + b.y * b.y);
    o.z = sqrtf(a.z * a.z + b.z * b.z);
    o.w = sqrtf(a.w * a.w + b.w * b.w);
    ((float4*)mag)[i] = o;
  }
}

// ------------------------------------------------------------- pattern ----
__global__ __launch_bounds__(256) void k_patt(const float* __restrict__ stored,
                                              const float* __restrict__ mag,
                                              float* __restrict__ patt, int n4) {
  int i = blockIdx.x * blockDim.x + threadIdx.x;
  if (i < n4) {
    int d4 = i & (DIM / 4 - 1);
    int p  = (i >> 8) % PT;
    int b  = i / (PT * (DIM / 4));
    float4 v;
    if (p < P0) {
      v = ((const float4*)stored)[(size_t)p * (DIM / 4) + d4];
    } else {
      v = ((const float4*)mag)[((size_t)(b * S + (p - P0))) * (DIM / 4) + d4];
    }
    ((float4*)patt)[i] = v;
  }
}

// ---------------------------------------------- plain hi/lo bf16 split ----
__global__ __launch_bounds__(256) void k_split_plain(const float* __restrict__ X,
                                                     unsigned short* __restrict__ hi,
                                                     unsigned short* __restrict__ lo,
                                                     int n4) {
  int i = blockIdx.x * 256 + threadIdx.x;
  if (i >= n4) return;
  float4 v = ((const float4*)X)[(size_t)i];
  float xs[4] = {v.x, v.y, v.z, v.w};
  ushort4v hv, lv;
#pragma unroll
  for (int j = 0; j < 4; ++j) {
    unsigned short hb = bf16_rne(xs[j]);
    hv[j] = hb;
    lv[j] = bf16_rne(xs[j] - bf16_f(hb));
  }
  ((ushort4v*)hi)[(size_t)i] = hv;
  ((ushort4v*)lo)[(size_t)i] = lv;
}

// ------------------------------------------------------- MFMA GEMM --------
// C(M,N) = A @ W^T with A,W pre-split hi/lo bf16 row-major (K-contig).
// 128x128 tile, BK=32, 256 threads = 4 waves (2x2), 3-product split.
__global__ __launch_bounds__(256, 2) void k_gemm_mfma(
    const unsigned short* __restrict__ Ah, const unsigned short* __restrict__ Al,
    const unsigned short* __restrict__ Wh, const unsigned short* __restrict__ Wl,
    const float* __restrict__ bias, float* __restrict__ Cf,
    unsigned short* __restrict__ Ohi, unsigned short* __restrict__ Olo,
    int M, int N, int K, int mode, int rpb, int aremap) {
  __shared__ short8v lds[4][4 * 132];   // Ah, Al, Wh, Wl frag-major tiles
  const int t = threadIdx.x;
  const int w = t >> 6, lane = t & 63;
  const int l16 = lane & 15, l4 = lane >> 4;
  const int wr = w >> 1, wc = w & 1;
  const int bm = blockIdx.y, bn = blockIdx.x;

  f32x4 acc[4][4];
#pragma unroll
  for (int mi = 0; mi < 4; ++mi)
#pragma unroll
    for (int nj = 0; nj < 4; ++nj) acc[mi][nj] = (f32x4){0.f, 0.f, 0.f, 0.f};

  for (int k0 = 0; k0 < K; k0 += 32) {
    __syncthreads();
#pragma unroll
    for (int rep = 0; rep < 2; ++rep) {
      int u = rep * 256 + t;
      int kb = u & 3, r = u >> 2;
      int agr = bm * 128 + r;
      int ar = aremap ? (agr + 512 + ((agr >> 10) << 9)) : agr;
      size_t ga = (size_t)ar * K + k0 + kb * 8;
      size_t gw = (size_t)(bn * 128 + r) * K + k0 + kb * 8;
      int li = kb * 132 + r;
      lds[0][li] = *(const short8v*)(Ah + ga);
      lds[1][li] = *(const short8v*)(Al + ga);
      lds[2][li] = *(const short8v*)(Wh + gw);
      lds[3][li] = *(const short8v*)(Wl + gw);
    }
    __syncthreads();
    short8v af[4][2], bf[4][2];
#pragma unroll
    for (int mi = 0; mi < 4; ++mi) {
      int li = l4 * 132 + wr * 64 + mi * 16 + l16;
      af[mi][0] = lds[0][li];
      af[mi][1] = lds[1][li];
    }
#pragma unroll
    for (int nj = 0; nj < 4; ++nj) {
      int li = l4 * 132 + wc * 64 + nj * 16 + l16;
      bf[nj][0] = lds[2][li];
      bf[nj][1] = lds[3][li];
    }
#pragma unroll
    for (int mi = 0; mi < 4; ++mi)
#pragma unroll
      for (int nj = 0; nj < 4; ++nj) {
        acc[mi][nj] = __builtin_amdgcn_mfma_f32_16x16x32_bf16(af[mi][0], bf[nj][0], acc[mi][nj], 0, 0, 0);
        acc[mi][nj] = __builtin_amdgcn_mfma_f32_16x16x32_bf16(af[mi][0], bf[nj][1], acc[mi][nj], 0, 0, 0);
        acc[mi][nj] = __builtin_amdgcn_mfma_f32_16x16x32_bf16(af[mi][1], bf[nj][0], acc[mi][nj], 0, 0, 0);
      }
  }

#pragma unroll
  for (int mi = 0; mi < 4; ++mi)
#pragma unroll
    for (int nj = 0; nj < 4; ++nj)
#pragma unroll
      for (int i = 0; i < 4; ++i) {
        int rg = bm * 128 + wr * 64 + mi * 16 + l4 * 4 + i;
        int c  = bn * 128 + wc * 64 + nj * 16 + l16;
        float v = acc[mi][nj][i];
        if (mode == 0) {
          Cf[(size_t)rg * N + c] = v + (bias ? bias[c] : 0.f);
        } else {
          int b = rg >= rpb ? 1 : 0;
          int p = rg - b * rpb;
          int hh = c >> 6, d = c & 63;
          size_t o = (mode == 1)
                         ? ((((size_t)(b * 16 + hh)) * rpb + p) * 64 + d)
                         : ((((size_t)(b * 16 + hh)) * 64 + d) * (size_t)rpb + p);
          unsigned short hb = bf16_rne(v);
          Ohi[o] = hb;
          Olo[o] = bf16_rne(v - bf16_f(hb));
        }
      }
}

// --------------------------------------- fused MFMA attention (3 steps) ----
// Block = 16 query rows of one (b,h), 512 threads = 8 waves, loops STEPS=3
// internally (K,V fixed; rows independent -> no global sync needed).
// Swapped QK^T: mfma(K_frag, state_frag) -> score tile transposed so each
// lane's 48 score regs all belong to row l16. Sparsemax reductions: 2 shfl
// stages (xor 16,32) + cross-wave part[]; tau is a per-lane scalar.
// State passes between iterations via stateLds (4.4 KB).
#define WSTR 40  // ushort stride of wbuf rows

__global__ __launch_bounds__(512, 4) void k_attn_fused(
    const unsigned short* __restrict__ qhi, const unsigned short* __restrict__ qlo,
    const unsigned short* __restrict__ khi, const unsigned short* __restrict__ klo,
    const unsigned short* __restrict__ vthi, const unsigned short* __restrict__ vtlo,
    const float* __restrict__ log_temp,
    unsigned short* __restrict__ swhi, unsigned short* __restrict__ swlo) {
  __shared__ float part[8][2][2][20];             // 5120 B reduction scratch
  __shared__ unsigned short wbufh[8][16 * WSTR];  // 10240 B per-wave weights hi
  __shared__ unsigned short wbufl[8][16 * WSTR];  // 10240 B per-wave weights lo
  __shared__ float red2[8][16][20];               // 10240 B dt-chunked reduce
  __shared__ float stateLds[16][68];              // 4352 B inter-step state
  const int t = threadIdx.x;
  const int w = t >> 6, lane = t & 63;
  const int l16 = lane & 15, l4 = lane >> 4;
  // XCD-aware bijective swizzle (2048 % 8 == 0)
  const int bid = blockIdx.x;
  const int tile = (bid & 7) * 256 + (bid >> 3);
  const int stile = tile & 63;
  const int bh = tile >> 6;
  const int h = bh & 15;
  const int s0 = stile * 16;

  float lt = log_temp[h];
  lt = fminf(fmaxf(lt, -4.f), 4.f);
  const float inv_scale = 1.f / (8.f * expf(lt));

  // state B-fragments: col = l16 = row s, k = 8*l4+j over d
  const size_t arow = ((size_t)bh * S + s0 + l16) * HD + 8 * l4;
  short8v ahi0 = *(const short8v*)(qhi + arow);
  short8v ahi1 = *(const short8v*)(qhi + arow + 32);
  short8v alo0 = *(const short8v*)(qlo + arow);
  short8v alo1 = *(const short8v*)(qlo + arow + 32);

  const size_t kb = (size_t)bh * PT * HD;
  const size_t vb = (size_t)bh * HD * PT;

  for (int step = 0; step < 3; ++step) {
    // ---- QK^T (swapped): z[p-local][row l16]; lane holds row l16 only ----
    float z0[6][4], z1[6][4];
#pragma unroll
    for (int pp = 0; pp < 6; ++pp) {
      const int pt0 = w * 12 + pp * 2;
      const size_t k0 = kb + ((size_t)(pt0 * 16 + l16)) * HD + 8 * l4;
      const size_t k1 = k0 + 16 * HD;
      f32x4 a0 = {0.f, 0.f, 0.f, 0.f}, a1 = {0.f, 0.f, 0.f, 0.f};
      {
        short8v b00 = *(const short8v*)(khi + k0);
        short8v b01 = *(const short8v*)(khi + k0 + 32);
        short8v b10 = *(const short8v*)(khi + k1);
        short8v b11 = *(const short8v*)(khi + k1 + 32);
        a0 = __builtin_amdgcn_mfma_f32_16x16x32_bf16(b00, ahi0, a0, 0, 0, 0);
        a1 = __builtin_amdgcn_mfma_f32_16x16x32_bf16(b10, ahi0, a1, 0, 0, 0);
        a0 = __builtin_amdgcn_mfma_f32_16x16x32_bf16(b01, ahi1, a0, 0, 0, 0);
        a1 = __builtin_amdgcn_mfma_f32_16x16x32_bf16(b11, ahi1, a1, 0, 0, 0);
        a0 = __builtin_amdgcn_mfma_f32_16x16x32_bf16(b00, alo0, a0, 0, 0, 0);
        a1 = __builtin_amdgcn_mfma_f32_16x16x32_bf16(b10, alo0, a1, 0, 0, 0);
        a0 = __builtin_amdgcn_mfma_f32_16x16x32_bf16(b01, alo1, a0, 0, 0, 0);
        a1 = __builtin_amdgcn_mfma_f32_16x16x32_bf16(b11, alo1, a1, 0, 0, 0);
      }
      {
        short8v c00 = *(const short8v*)(klo + k0);
        short8v c01 = *(const short8v*)(klo + k0 + 32);
        short8v c10 = *(const short8v*)(klo + k1);
        short8v c11 = *(const short8v*)(klo + k1 + 32);
        a0 = __builtin_amdgcn_mfma_f32_16x16x32_bf16(c00, ahi0, a0, 0, 0, 0);
        a1 = __builtin_amdgcn_mfma_f32_16x16x32_bf16(c10, ahi0, a1, 0, 0, 0);
        a0 = __builtin_amdgcn_mfma_f32_16x16x32_bf16(c01, ahi1, a0, 0, 0, 0);
        a1 = __builtin_amdgcn_mfma_f32_16x16x32_bf16(c11, ahi1, a1, 0, 0, 0);
      }
      const int sg = s0 + l16;
#pragma unroll
      for (int i = 0; i < 4; ++i) {
        const int p0i = pt0 * 16 + l4 * 4 + i;   // C row = p within tile
        z0[pp][i] = (p0i > P0 + sg) ? -1e9f : a0[i] * inv_scale;
        z1[pp][i] = (p0i + 16 > P0 + sg) ? -1e9f : a1[i] * inv_scale;
      }
    }

    // ---- row max (scalar per lane: row = l16) ----
    float mxv = -1e30f;
#pragma unroll
    for (int pp = 0; pp < 6; ++pp)
#pragma unroll
      for (int i = 0; i < 4; ++i) mxv = fmaxf(mxv, fmaxf(z0[pp][i], z1[pp][i]));
    mxv = fmaxf(mxv, __shfl_xor(mxv, 16, 64));
    mxv = fmaxf(mxv, __shfl_xor(mxv, 32, 64));
    if (lane < 16) part[w][0][0][lane] = mxv;
    __syncthreads();
    float gm = -1e30f;
#pragma unroll
    for (int ww = 0; ww < 8; ++ww) gm = fmaxf(gm, part[ww][0][0][l16]);
    float tlo = gm - 1.f, thi = gm;

    // ---- bisection: 10 rounds, parity-buffered ----
    for (int it = 0; it < 10; ++it) {
      const int sl = (it + 1) & 1;
      const float mid = 0.5f * (tlo + thi);
      float s = 0.f;
#pragma unroll
      for (int pp = 0; pp < 6; ++pp)
#pragma unroll
        for (int i = 0; i < 4; ++i)
          s += fmaxf(z0[pp][i] - mid, 0.f) + fmaxf(z1[pp][i] - mid, 0.f);
      s += __shfl_xor(s, 16, 64);
      s += __shfl_xor(s, 32, 64);
      if (lane < 16) part[w][sl][0][lane] = s;
      __syncthreads();
      float rs = 0.f;
#pragma unroll
      for (int ww = 0; ww < 8; ++ww) rs += part[ww][sl][0][l16];
      if (rs >= 1.f) tlo = mid; else thi = mid;
    }

    // ---- Michelot exact finalize: 4 rounds ----
    float tau = tlo;
    for (int it = 0; it < 4; ++it) {
      const int sl = (11 + it) & 1;
      float c = 0.f, s = 0.f;
#pragma unroll
      for (int pp = 0; pp < 6; ++pp)
#pragma unroll
        for (int i = 0; i < 4; ++i) {
          float a = z0[pp][i];
          if (a > tau) { c += 1.f; s += a; }
          float b2 = z1[pp][i];
          if (b2 > tau) { c += 1.f; s += b2; }
        }
      c += __shfl_xor(c, 16, 64);
      c += __shfl_xor(c, 32, 64);
      s += __shfl_xor(s, 16, 64);
      s += __shfl_xor(s, 32, 64);
      if (lane < 16) {
        part[w][sl][0][lane] = c;
        part[w][sl][1][lane] = s;
      }
      __syncthreads();
      float rc = 0.f, rs = 0.f;
#pragma unroll
      for (int ww = 0; ww < 8; ++ww) {
        rc += part[ww][sl][0][l16];
        rs += part[ww][sl][1][l16];
      }
      tau = (rs - 1.f) / rc;
    }

    // ---- PV: per-kk weight stage (rows l16 lane-local -> A-frag rows) ----
    f32x4 acc[4];
#pragma unroll
    for (int dt = 0; dt < 4; ++dt) acc[dt] = (f32x4){0.f, 0.f, 0.f, 0.f};
    unsigned short* wh = wbufh[w];
    unsigned short* wl = wbufl[w];
#pragma unroll
    for (int kk = 0; kk < 6; ++kk) {
      const int ks = w * 6 + kk;
      ushort4v h0v, l0v, h1v, l1v;
#pragma unroll
      for (int i = 0; i < 4; ++i) {
        float w0 = fmaxf(z0[kk][i] - tau, 0.f);
        float w1 = fmaxf(z1[kk][i] - tau, 0.f);
        unsigned short hb0 = bf16_rne(w0);
        unsigned short hb1 = bf16_rne(w1);
        h0v[i] = hb0; l0v[i] = bf16_rne(w0 - bf16_f(hb0));
        h1v[i] = hb1; l1v[i] = bf16_rne(w1 - bf16_f(hb1));
      }
      *(ushort4v*)(wh + l16 * WSTR + l4 * 4) = h0v;
      *(ushort4v*)(wh + l16 * WSTR + 16 + l4 * 4) = h1v;
      *(ushort4v*)(wl + l16 * WSTR + l4 * 4) = l0v;
      *(ushort4v*)(wl + l16 * WSTR + 16 + l4 * 4) = l1v;
      asm volatile("s_waitcnt lgkmcnt(0)" ::: "memory");  // wave-local W->R
      __builtin_amdgcn_sched_barrier(0);
      short8v wah = *(const short8v*)(wh + l16 * WSTR + 8 * l4);
      short8v wal = *(const short8v*)(wl + l16 * WSTR + 8 * l4);
#pragma unroll
      for (int dt = 0; dt < 4; ++dt) {
        const size_t vo = vb + (size_t)(dt * 16 + l16) * PT + ks * 32 + 8 * l4;
        short8v vh = *(const short8v*)(vthi + vo);
        short8v vl = *(const short8v*)(vtlo + vo);
        acc[dt] = __builtin_amdgcn_mfma_f32_16x16x32_bf16(wah, vh, acc[dt], 0, 0, 0);
        acc[dt] = __builtin_amdgcn_mfma_f32_16x16x32_bf16(wah, vl, acc[dt], 0, 0, 0);
        acc[dt] = __builtin_amdgcn_mfma_f32_16x16x32_bf16(wal, vh, acc[dt], 0, 0, 0);
      }
    }

    // ---- cross-wave reduce, dt-chunked; state to LDS (or global last) ----
    for (int dt = 0; dt < 4; ++dt) {
      __syncthreads();
#pragma unroll
      for (int i = 0; i < 4; ++i)
        red2[w][l4 * 4 + i][l16] = acc[dt][i];
      __syncthreads();
      if (t < 256) {
        const int row = t >> 4, d16 = t & 15;
        float sum = 0.f;
#pragma unroll
        for (int ww = 0; ww < 8; ++ww) sum += red2[ww][row][d16];
        const int d = dt * 16 + d16;
        if (step == 2) {
          const int sg = s0 + row;
          unsigned short hb = bf16_rne(sum);
          const size_t rw = ((size_t)((bh >> 4) * S + sg)) * DIM + h * HD + d;
          swhi[rw] = hb;
          swlo[rw] = bf16_rne(sum - bf16_f(hb));
        } else {
          stateLds[row][d] = sum;
        }
      }
    }

    // ---- reload state fragments from LDS for next iteration ----
    if (step < 2) {
      __syncthreads();
      float xs[16];
      *(f32x4*)&xs[0]  = *(const f32x4*)&stateLds[l16][8 * l4];
      *(f32x4*)&xs[4]  = *(const f32x4*)&stateLds[l16][8 * l4 + 4];
      *(f32x4*)&xs[8]  = *(const f32x4*)&stateLds[l16][32 + 8 * l4];
      *(f32x4*)&xs[12] = *(const f32x4*)&stateLds[l16][32 + 8 * l4 + 4];
      ushort8v h0, l0, h1, l1;
#pragma unroll
      for (int j = 0; j < 8; ++j) {
        unsigned short hb = bf16_rne(xs[j]);
        h0[j] = hb; l0[j] = bf16_rne(xs[j] - bf16_f(hb));
        unsigned short hb2 = bf16_rne(xs[8 + j]);
        h1[j] = hb2; l1[j] = bf16_rne(xs[8 + j] - bf16_f(hb2));
      }
      ahi0 = __builtin_bit_cast(short8v, h0);
      alo0 = __builtin_bit_cast(short8v, l0);
      ahi1 = __builtin_bit_cast(short8v, h1);
      alo1 = __builtin_bit_cast(short8v, l1);
      __syncthreads();   // frag reads done before next iter reuses LDS
    }
  }
}

// ----------------------------------------------------------- layernorm ----
__global__ __launch_bounds__(256) void k_layernorm(float* __restrict__ out,
                                                   const float* __restrict__ gamma,
                                                   const float* __restrict__ beta) {
  const int W = 2 * DIM;
  const int r = blockIdx.x;
  float* row = out + (size_t)r * W;
  const int t = threadIdx.x;
  float4 vals[2];
  float sum = 0.f, sq = 0.f;
#pragma unroll
  for (int i = 0; i < 2; ++i) {
    float4 v = *(const float4*)(row + (i * 256 + t) * 4);
    vals[i] = v;
    sum += v.x + v.y + v.z + v.w;
    sq += v.x * v.x + v.y * v.y + v.z * v.z + v.w * v.w;
  }
#pragma unroll
  for (int off = 32; off >= 1; off >>= 1) {
    sum += __shfl_xor(sum, off, 64);
    sq  += __shfl_xor(sq,  off, 64);
  }
  __shared__ float rs[4], rq[4];
  const int wave = t >> 6, lane = t & 63;
  if (lane == 0) { rs[wave] = sum; rq[wave] = sq; }
  __syncthreads();
  sum = rs[0] + rs[1] + rs[2] + rs[3];
  sq  = rq[0] + rq[1] + rq[2] + rq[3];
  const float mean = sum / W;
  const float var = sq / W - mean * mean;
  const float rstd = rsqrtf(var + 1e-5f);
#pragma unroll
  for (int i = 0; i < 2; ++i) {
    int base = (i * 256 + t) * 4;
    float4 v = vals[i];
    float4 g = *(const float4*)(gamma + base);
    float4 bb = *(const float4*)(beta + base);
    v.x = (v.x - mean) * rstd * g.x + bb.x;
    v.y = (v.y - mean) * rstd * g.y + bb.y;
    v.z = (v.z - mean) * rstd * g.z + bb.z;
    v.w = (v.w - mean) * rstd * g.w + bb.w;
    *(float4*)(row + base) = v;
  }
}

// ---------------------------------------------------------------- launch --
extern "C" void kernel_launch(void* const* d_in, const int* in_sizes, int n_in,
                              void* d_out, int out_size, void* d_ws, size_t ws_size,
                              hipStream_t stream) {
  const float* zr       = (const float*)d_in[0];
  const float* zi       = (const float*)d_in[1];
  const float* stored   = (const float*)d_in[3];
  const float* Wq       = (const float*)d_in[4];
  const float* Wk       = (const float*)d_in[5];
  const float* Wv       = (const float*)d_in[6];
  const float* Wo       = (const float*)d_in[7];
  const float* bo       = (const float*)d_in[8];
  const float* log_temp = (const float*)d_in[9];
  const float* gamma    = (const float*)d_in[10];
  const float* beta     = (const float*)d_in[11];
  float* out = (float*)d_out;

  // --- workspace layout, 64 MB peak with lifetime overlays ---
  char* base = (char*)d_ws;
  float* patt = (float*)(base + (size_t)0);                       // 0-12 MB
  unsigned short* vthi = (unsigned short*)(base + (size_t)0);     // 0-6  (over dead patt)
  unsigned short* vtlo = (unsigned short*)(base + (6u << 20));    // 6-12
  unsigned short* phi  = (unsigned short*)(base + (12u << 20));   // 12-18
  unsigned short* plo  = (unsigned short*)(base + (18u << 20));   // 18-24
  unsigned short* swhi = (unsigned short*)(base + (12u << 20));   // 12-16 (over dead phi/plo)
  unsigned short* swlo = (unsigned short*)(base + (16u << 20));   // 16-20
  unsigned short* wqh  = (unsigned short*)(base + (24u << 20));   // 24-26
  unsigned short* wql  = (unsigned short*)(base + (26u << 20));   // 26-28
  unsigned short* wkh  = (unsigned short*)(base + (28u << 20));   // 28-30
  unsigned short* wkl  = (unsigned short*)(base + (30u << 20));   // 30-32
  unsigned short* wvh  = (unsigned short*)(base + (32u << 20));   // 32-34
  unsigned short* wvl  = (unsigned short*)(base + (34u << 20));   // 34-36
  unsigned short* woh  = (unsigned short*)(base + (24u << 20));   // 24-28 (over dead wq/wk)
  unsigned short* wol  = (unsigned short*)(base + (28u << 20));   // 28-32
  float* mag = (float*)(base + (36u << 20));                      // 36-44
  unsigned short* qhi = (unsigned short*)(base + (36u << 20));    // 36-40 (over dead mag)
  unsigned short* qlo = (unsigned short*)(base + (40u << 20));    // 40-44
  unsigned short* khi  = (unsigned short*)(base + (52u << 20));   // 52-58
  unsigned short* klo  = (unsigned short*)(base + (58u << 20));   // 58-64

  const int n4 = B * S * DIM / 4;            // 524288
  k_mag<<<(n4 + 255) / 256, 256, 0, stream>>>(zr, zi, mag, n4);
  const int p4 = B * PT * DIM / 4;           // 786432
  k_patt<<<(p4 + 255) / 256, 256, 0, stream>>>(stored, mag, patt, p4);

  // splits: patterns + projection weights
  k_split_plain<<<p4 / 256, 256, 0, stream>>>(patt, phi, plo, p4);
  const int w4 = DIM * DIM / 4;              // 262144
  k_split_plain<<<w4 / 256, 256, 0, stream>>>(Wq, wqh, wql, w4);
  k_split_plain<<<w4 / 256, 256, 0, stream>>>(Wk, wkh, wkl, w4);
  k_split_plain<<<w4 / 256, 256, 0, stream>>>(Wv, wvh, wvl, w4);

  // Q = mag @ Wq^T  (A rows remapped into patt), head-major hi/lo out
  dim3 gq(1024 / 128, 2048 / 128);
  k_gemm_mfma<<<gq, 256, 0, stream>>>(phi, plo, wqh, wql, nullptr, nullptr,
                                      qhi, qlo, 2048, 1024, 1024, 1, 1024, 1);
  // K = patt @ Wk^T, head-major hi/lo out
  dim3 gkv(1024 / 128, 3072 / 128);
  k_gemm_mfma<<<gkv, 256, 0, stream>>>(phi, plo, wkh, wkl, nullptr, nullptr,
                                       khi, klo, 3072, 1024, 1024, 1, 1536, 0);
  // V = patt @ Wv^T, V^T hi/lo out
  k_gemm_mfma<<<gkv, 256, 0, stream>>>(phi, plo, wvh, wvl, nullptr, nullptr,
                                       vthi, vtlo, 3072, 1024, 1024, 2, 1536, 0);

  // Wo split (after wq/wk dead)
  const int wo4 = 2 * DIM * DIM / 4;         // 524288
  k_split_plain<<<wo4 / 256, 256, 0, stream>>>(Wo, woh, wol, wo4);

  // fused 3-step Hopfield attention
  k_attn_fused<<<B * H * (S / 16), 512, 0, stream>>>(qhi, qlo, khi, klo,
                                                     vthi, vtlo, log_temp,
                                                     swhi, swlo);

  // out = sw @ Wo^T + bo, fp32
  dim3 go(2048 / 128, 2048 / 128);
  k_gemm_mfma<<<go, 256, 0, stream>>>(swhi, swlo, woh, wol, bo, out,
                                      nullptr, nullptr, 2048, 2048, 1024, 0, 0, 0);
  k_layernorm<<<B * S, 256, 0, stream>>>(out, gamma, beta);
}

// Round 9
// 747.958 us; speedup vs baseline: 1.4005x; 1.4005x over previous
//
#include <hip/hip_runtime.h>
#include <math.h>

#define DIM 1024
#define P0 512
#define H 16
#define HD 64
#define B 2
#define S 1024
#define PT 1536   // P0 + S

typedef __attribute__((ext_vector_type(8))) short short8v;    // bf16 MFMA frag
typedef __attribute__((ext_vector_type(4))) float f32x4;
typedef __attribute__((ext_vector_type(8))) unsigned short ushort8v;
typedef __attribute__((ext_vector_type(4))) unsigned short ushort4v;

__device__ __forceinline__ unsigned short bf16_rne(float x) {
  unsigned u = __builtin_bit_cast(unsigned, x);
  u += 0x7FFFu + ((u >> 16) & 1u);
  return (unsigned short)(u >> 16);
}
__device__ __forceinline__ float bf16_f(unsigned short h) {
  unsigned u = ((unsigned)h) << 16;
  return __builtin_bit_cast(float, u);
}

// ---------------------------------------------------------------- mag ----
__global__ __launch_bounds__(256) void k_mag(const float* __restrict__ zr,
                                             const float* __restrict__ zi,
                                             float* __restrict__ mag, int n4) {
  int i = blockIdx.x * blockDim.x + threadIdx.x;
  if (i < n4) {
    float4 a = ((const float4*)zr)[i];
    float4 b = ((const float4*)zi)[i];
    float4 o;
    o.x = sqrtf(a.x * a.x + b.x * b.x);
    o.y = sqrtf(a.y * a.y + b.y * b.y);
    o.z = sqrtf(a.z * a.z + b.z * b.z);
    o.w = sqrtf(a.w * a.w + b.w * b.w);
    ((float4*)mag)[i] = o;
  }
}

// ------------------------------------------------------------- pattern ----
__global__ __launch_bounds__(256) void k_patt(const float* __restrict__ stored,
                                              const float* __restrict__ mag,
                                              float* __restrict__ patt, int n4) {
  int i = blockIdx.x * blockDim.x + threadIdx.x;
  if (i < n4) {
    int d4 = i & (DIM / 4 - 1);
    int p  = (i >> 8) % PT;
    int b  = i / (PT * (DIM / 4));
    float4 v;
    if (p < P0) {
      v = ((const float4*)stored)[(size_t)p * (DIM / 4) + d4];
    } else {
      v = ((const float4*)mag)[((size_t)(b * S + (p - P0))) * (DIM / 4) + d4];
    }
    ((float4*)patt)[i] = v;
  }
}

// ---------------------------------------------- plain hi/lo bf16 split ----
__global__ __launch_bounds__(256) void k_split_plain(const float* __restrict__ X,
                                                     unsigned short* __restrict__ hi,
                                                     unsigned short* __restrict__ lo,
                                                     int n4) {
  int i = blockIdx.x * 256 + threadIdx.x;
  if (i >= n4) return;
  float4 v = ((const float4*)X)[(size_t)i];
  float xs[4] = {v.x, v.y, v.z, v.w};
  ushort4v hv, lv;
#pragma unroll
  for (int j = 0; j < 4; ++j) {
    unsigned short hb = bf16_rne(xs[j]);
    hv[j] = hb;
    lv[j] = bf16_rne(xs[j] - bf16_f(hb));
  }
  ((ushort4v*)hi)[(size_t)i] = hv;
  ((ushort4v*)lo)[(size_t)i] = lv;
}

// ------------------------------------------------------- MFMA GEMM --------
// C(M,N) = A @ W^T with A,W pre-split hi/lo bf16 row-major (K-contig).
// 128x128 tile, BK=32, 256 threads = 4 waves (2x2), 3-product split.
__global__ __launch_bounds__(256, 2) void k_gemm_mfma(
    const unsigned short* __restrict__ Ah, const unsigned short* __restrict__ Al,
    const unsigned short* __restrict__ Wh, const unsigned short* __restrict__ Wl,
    const float* __restrict__ bias, float* __restrict__ Cf,
    unsigned short* __restrict__ Ohi, unsigned short* __restrict__ Olo,
    int M, int N, int K, int mode, int rpb, int aremap) {
  __shared__ short8v lds[4][4 * 132];   // Ah, Al, Wh, Wl frag-major tiles
  const int t = threadIdx.x;
  const int w = t >> 6, lane = t & 63;
  const int l16 = lane & 15, l4 = lane >> 4;
  const int wr = w >> 1, wc = w & 1;
  const int bm = blockIdx.y, bn = blockIdx.x;

  f32x4 acc[4][4];
#pragma unroll
  for (int mi = 0; mi < 4; ++mi)
#pragma unroll
    for (int nj = 0; nj < 4; ++nj) acc[mi][nj] = (f32x4){0.f, 0.f, 0.f, 0.f};

  for (int k0 = 0; k0 < K; k0 += 32) {
    __syncthreads();
#pragma unroll
    for (int rep = 0; rep < 2; ++rep) {
      int u = rep * 256 + t;
      int kb = u & 3, r = u >> 2;
      int agr = bm * 128 + r;
      int ar = aremap ? (agr + 512 + ((agr >> 10) << 9)) : agr;
      size_t ga = (size_t)ar * K + k0 + kb * 8;
      size_t gw = (size_t)(bn * 128 + r) * K + k0 + kb * 8;
      int li = kb * 132 + r;
      lds[0][li] = *(const short8v*)(Ah + ga);
      lds[1][li] = *(const short8v*)(Al + ga);
      lds[2][li] = *(const short8v*)(Wh + gw);
      lds[3][li] = *(const short8v*)(Wl + gw);
    }
    __syncthreads();
    short8v af[4][2], bf[4][2];
#pragma unroll
    for (int mi = 0; mi < 4; ++mi) {
      int li = l4 * 132 + wr * 64 + mi * 16 + l16;
      af[mi][0] = lds[0][li];
      af[mi][1] = lds[1][li];
    }
#pragma unroll
    for (int nj = 0; nj < 4; ++nj) {
      int li = l4 * 132 + wc * 64 + nj * 16 + l16;
      bf[nj][0] = lds[2][li];
      bf[nj][1] = lds[3][li];
    }
#pragma unroll
    for (int mi = 0; mi < 4; ++mi)
#pragma unroll
      for (int nj = 0; nj < 4; ++nj) {
        acc[mi][nj] = __builtin_amdgcn_mfma_f32_16x16x32_bf16(af[mi][0], bf[nj][0], acc[mi][nj], 0, 0, 0);
        acc[mi][nj] = __builtin_amdgcn_mfma_f32_16x16x32_bf16(af[mi][0], bf[nj][1], acc[mi][nj], 0, 0, 0);
        acc[mi][nj] = __builtin_amdgcn_mfma_f32_16x16x32_bf16(af[mi][1], bf[nj][0], acc[mi][nj], 0, 0, 0);
      }
  }

#pragma unroll
  for (int mi = 0; mi < 4; ++mi)
#pragma unroll
    for (int nj = 0; nj < 4; ++nj)
#pragma unroll
      for (int i = 0; i < 4; ++i) {
        int rg = bm * 128 + wr * 64 + mi * 16 + l4 * 4 + i;
        int c  = bn * 128 + wc * 64 + nj * 16 + l16;
        float v = acc[mi][nj][i];
        if (mode == 0) {
          Cf[(size_t)rg * N + c] = v + (bias ? bias[c] : 0.f);
        } else {
          int b = rg >= rpb ? 1 : 0;
          int p = rg - b * rpb;
          int hh = c >> 6, d = c & 63;
          size_t o = (mode == 1)
                         ? ((((size_t)(b * 16 + hh)) * rpb + p) * 64 + d)
                         : ((((size_t)(b * 16 + hh)) * 64 + d) * (size_t)rpb + p);
          unsigned short hb = bf16_rne(v);
          Ohi[o] = hb;
          Olo[o] = bf16_rne(v - bf16_f(hb));
        }
      }
}

// ------------------------------------------------- MFMA attention step ----
// One Hopfield iteration (3 dispatches/launch -> short register lifetimes,
// no spill). Block = 16 query rows of one (b,h), 512 threads = 8 waves.
// Swapped QK^T: mfma(K_frag, state_frag) -> lane's 48 score regs all belong
// to query row l16; sparsemax reductions are scalar with 2 shfl stages.
// Interleaved tile ownership: wave w owns tiles {w, w+8, ...}; tiles with
// index > stile+33 are fully causal-masked and SKIPPED (MFMA + all scan
// passes + PV) -> ~32% average work cut, balanced across waves.
#define WSTR 40  // ushort stride of wbuf rows

__global__ __launch_bounds__(512, 4) void k_attn_mfma(
    const unsigned short* __restrict__ shi, const unsigned short* __restrict__ slo,
    const unsigned short* __restrict__ khi, const unsigned short* __restrict__ klo,
    const unsigned short* __restrict__ vthi, const unsigned short* __restrict__ vtlo,
    const float* __restrict__ log_temp,
    unsigned short* __restrict__ swhi, unsigned short* __restrict__ swlo,
    unsigned short* __restrict__ ohi, unsigned short* __restrict__ olo) {
  __shared__ float part[8][2][2][20];             // 5120 B reduction scratch
  __shared__ unsigned short wbufh[8][16 * WSTR];  // 10240 B per-wave weights hi
  __shared__ unsigned short wbufl[8][16 * WSTR];  // 10240 B per-wave weights lo
  __shared__ float red2[8][16][20];               // 10240 B dt-chunked reduce
  const int t = threadIdx.x;
  const int w = t >> 6, lane = t & 63;
  const int l16 = lane & 15, l4 = lane >> 4;
  // XCD-aware bijective swizzle (2048 % 8 == 0)
  const int bid = blockIdx.x;
  const int tile = (bid & 7) * 256 + (bid >> 3);
  const int stile = tile & 63;
  const int bh = tile >> 6;
  const int h = bh & 15;
  const int s0 = stile * 16;
  const int maxTile = stile + 33;   // tile pt active iff pt <= maxTile

  float lt = log_temp[h];
  lt = fminf(fmaxf(lt, -4.f), 4.f);
  const float inv_scale = 1.f / (8.f * expf(lt));

  // state B-fragments (swapped mfma): col = l16 = query row, k = 8*l4+j
  const size_t arow = ((size_t)bh * S + s0 + l16) * HD + 8 * l4;
  short8v ahi0 = *(const short8v*)(shi + arow);
  short8v ahi1 = *(const short8v*)(shi + arow + 32);
  short8v alo0 = *(const short8v*)(slo + arow);
  short8v alo1 = *(const short8v*)(slo + arow + 32);

  const size_t kb = (size_t)bh * PT * HD;
  const size_t vb = (size_t)bh * HD * PT;
  const int sg = s0 + l16;

  // ---- QK^T (swapped, interleaved tiles, causal tile-skip) ----
  float z0[6][4], z1[6][4];
#pragma unroll
  for (int j = 0; j < 6; ++j) {
    const int tA = w + 16 * j, tB = tA + 8;
    if (tA > maxTile) {          // whole pair fully masked (wave-uniform)
#pragma unroll
      for (int i = 0; i < 4; ++i) { z0[j][i] = -1e9f; z1[j][i] = -1e9f; }
    } else {
      const size_t k0 = kb + ((size_t)(tA * 16 + l16)) * HD + 8 * l4;
      f32x4 a0 = {0.f, 0.f, 0.f, 0.f};
      {
        short8v b00 = *(const short8v*)(khi + k0);
        short8v b01 = *(const short8v*)(khi + k0 + 32);
        short8v c00 = *(const short8v*)(klo + k0);
        short8v c01 = *(const short8v*)(klo + k0 + 32);
        a0 = __builtin_amdgcn_mfma_f32_16x16x32_bf16(b00, ahi0, a0, 0, 0, 0);
        a0 = __builtin_amdgcn_mfma_f32_16x16x32_bf16(b01, ahi1, a0, 0, 0, 0);
        a0 = __builtin_amdgcn_mfma_f32_16x16x32_bf16(b00, alo0, a0, 0, 0, 0);
        a0 = __builtin_amdgcn_mfma_f32_16x16x32_bf16(b01, alo1, a0, 0, 0, 0);
        a0 = __builtin_amdgcn_mfma_f32_16x16x32_bf16(c00, ahi0, a0, 0, 0, 0);
        a0 = __builtin_amdgcn_mfma_f32_16x16x32_bf16(c01, ahi1, a0, 0, 0, 0);
      }
#pragma unroll
      for (int i = 0; i < 4; ++i) {
        const int pA = tA * 16 + l4 * 4 + i;
        z0[j][i] = (pA > P0 + sg) ? -1e9f : a0[i] * inv_scale;
      }
      if (tB <= maxTile) {
        const size_t k1 = kb + ((size_t)(tB * 16 + l16)) * HD + 8 * l4;
        f32x4 a1 = {0.f, 0.f, 0.f, 0.f};
        short8v b10 = *(const short8v*)(khi + k1);
        short8v b11 = *(const short8v*)(khi + k1 + 32);
        short8v c10 = *(const short8v*)(klo + k1);
        short8v c11 = *(const short8v*)(klo + k1 + 32);
        a1 = __builtin_amdgcn_mfma_f32_16x16x32_bf16(b10, ahi0, a1, 0, 0, 0);
        a1 = __builtin_amdgcn_mfma_f32_16x16x32_bf16(b11, ahi1, a1, 0, 0, 0);
        a1 = __builtin_amdgcn_mfma_f32_16x16x32_bf16(b10, alo0, a1, 0, 0, 0);
        a1 = __builtin_amdgcn_mfma_f32_16x16x32_bf16(b11, alo1, a1, 0, 0, 0);
        a1 = __builtin_amdgcn_mfma_f32_16x16x32_bf16(c10, ahi0, a1, 0, 0, 0);
        a1 = __builtin_amdgcn_mfma_f32_16x16x32_bf16(c11, ahi1, a1, 0, 0, 0);
#pragma unroll
        for (int i = 0; i < 4; ++i) {
          const int pB = tB * 16 + l4 * 4 + i;
          z1[j][i] = (pB > P0 + sg) ? -1e9f : a1[i] * inv_scale;
        }
      } else {
#pragma unroll
        for (int i = 0; i < 4; ++i) z1[j][i] = -1e9f;
      }
    }
  }

  // ---- row max (scalar per lane: row = l16) ----
  float mxv = -1e30f;
#pragma unroll
  for (int j = 0; j < 6; ++j) {
    if (w + 16 * j <= maxTile) {
#pragma unroll
      for (int i = 0; i < 4; ++i) mxv = fmaxf(mxv, fmaxf(z0[j][i], z1[j][i]));
    }
  }
  mxv = fmaxf(mxv, __shfl_xor(mxv, 16, 64));
  mxv = fmaxf(mxv, __shfl_xor(mxv, 32, 64));
  if (lane < 16) part[w][0][0][lane] = mxv;
  __syncthreads();
  float gm = -1e30f;
#pragma unroll
  for (int ww = 0; ww < 8; ++ww) gm = fmaxf(gm, part[ww][0][0][l16]);
  float tlo = gm - 1.f, thi = gm;

  // ---- bisection: 10 rounds, parity-buffered ----
  for (int it = 0; it < 10; ++it) {
    const int sl = (it + 1) & 1;
    const float mid = 0.5f * (tlo + thi);
    float s = 0.f;
#pragma unroll
    for (int j = 0; j < 6; ++j) {
      if (w + 16 * j <= maxTile) {
#pragma unroll
        for (int i = 0; i < 4; ++i)
          s += fmaxf(z0[j][i] - mid, 0.f) + fmaxf(z1[j][i] - mid, 0.f);
      }
    }
    s += __shfl_xor(s, 16, 64);
    s += __shfl_xor(s, 32, 64);
    if (lane < 16) part[w][sl][0][lane] = s;
    __syncthreads();
    float rs = 0.f;
#pragma unroll
    for (int ww = 0; ww < 8; ++ww) rs += part[ww][sl][0][l16];
    if (rs >= 1.f) tlo = mid; else thi = mid;
  }

  // ---- Michelot exact finalize: 4 rounds ----
  float tau = tlo;
  for (int it = 0; it < 4; ++it) {
    const int sl = (11 + it) & 1;
    float c = 0.f, s = 0.f;
#pragma unroll
    for (int j = 0; j < 6; ++j) {
      if (w + 16 * j <= maxTile) {
#pragma unroll
        for (int i = 0; i < 4; ++i) {
          float a = z0[j][i];
          if (a > tau) { c += 1.f; s += a; }
          float b2 = z1[j][i];
          if (b2 > tau) { c += 1.f; s += b2; }
        }
      }
    }
    c += __shfl_xor(c, 16, 64);
    c += __shfl_xor(c, 32, 64);
    s += __shfl_xor(s, 16, 64);
    s += __shfl_xor(s, 32, 64);
    if (lane < 16) {
      part[w][sl][0][lane] = c;
      part[w][sl][1][lane] = s;
    }
    __syncthreads();
    float rc = 0.f, rs = 0.f;
#pragma unroll
    for (int ww = 0; ww < 8; ++ww) {
      rc += part[ww][sl][0][l16];
      rs += part[ww][sl][1][l16];
    }
    tau = (rs - 1.f) / rc;
  }

  // ---- PV: per-pair weight stage + 3-product MFMA (skip masked pairs) ----
  f32x4 acc[4];
#pragma unroll
  for (int dt = 0; dt < 4; ++dt) acc[dt] = (f32x4){0.f, 0.f, 0.f, 0.f};
  unsigned short* wh = wbufh[w];
  unsigned short* wl = wbufl[w];
#pragma unroll
  for (int kk = 0; kk < 6; ++kk) {
    const int tA = w + 16 * kk, tB = tA + 8;
    if (tA > maxTile) continue;           // weights all zero (wave-uniform)
    ushort4v h0v, l0v, h1v, l1v;
#pragma unroll
    for (int i = 0; i < 4; ++i) {
      float w0 = fmaxf(z0[kk][i] - tau, 0.f);
      float w1 = fmaxf(z1[kk][i] - tau, 0.f);
      unsigned short hb0 = bf16_rne(w0);
      unsigned short hb1 = bf16_rne(w1);
      h0v[i] = hb0; l0v[i] = bf16_rne(w0 - bf16_f(hb0));
      h1v[i] = hb1; l1v[i] = bf16_rne(w1 - bf16_f(hb1));
    }
    *(ushort4v*)(wh + l16 * WSTR + l4 * 4) = h0v;        // k 0..15  = tile A
    *(ushort4v*)(wh + l16 * WSTR + 16 + l4 * 4) = h1v;   // k 16..31 = tile B
    *(ushort4v*)(wl + l16 * WSTR + l4 * 4) = l0v;
    *(ushort4v*)(wl + l16 * WSTR + 16 + l4 * 4) = l1v;
    asm volatile("s_waitcnt lgkmcnt(0)" ::: "memory");   // wave-local W->R
    __builtin_amdgcn_sched_barrier(0);
    short8v wah = *(const short8v*)(wh + l16 * WSTR + 8 * l4);
    short8v wal = *(const short8v*)(wl + l16 * WSTR + 8 * l4);
    // permuted k-order: lanes l4<2 read tile A's p-range, l4>=2 tile B's
    const int pbase = (l4 < 2) ? (tA * 16 + 8 * l4) : (tB * 16 + 8 * (l4 - 2));
#pragma unroll
    for (int dt = 0; dt < 4; ++dt) {
      const size_t vo = vb + (size_t)(dt * 16 + l16) * PT + pbase;
      short8v vh = *(const short8v*)(vthi + vo);
      short8v vl = *(const short8v*)(vtlo + vo);
      acc[dt] = __builtin_amdgcn_mfma_f32_16x16x32_bf16(wah, vh, acc[dt], 0, 0, 0);
      acc[dt] = __builtin_amdgcn_mfma_f32_16x16x32_bf16(wah, vl, acc[dt], 0, 0, 0);
      acc[dt] = __builtin_amdgcn_mfma_f32_16x16x32_bf16(wal, vh, acc[dt], 0, 0, 0);
    }
  }

  // ---- cross-wave reduce, dt-chunked (LDS-lean) + writes ----
  for (int dt = 0; dt < 4; ++dt) {
    __syncthreads();
#pragma unroll
    for (int i = 0; i < 4; ++i)
      red2[w][l4 * 4 + i][l16] = acc[dt][i];
    __syncthreads();
    if (t < 256) {
      const int row = t >> 4, d16 = t & 15;
      float sum = 0.f;
#pragma unroll
      for (int ww = 0; ww < 8; ++ww) sum += red2[ww][row][d16];
      const int d = dt * 16 + d16;
      const int sgr = s0 + row;
      unsigned short hb = bf16_rne(sum);
      unsigned short lb = bf16_rne(sum - bf16_f(hb));
      const size_t rw = ((size_t)((bh >> 4) * S + sgr)) * DIM + h * HD + d;
      swhi[rw] = hb;
      swlo[rw] = lb;
      const size_t oi = ((size_t)bh * S + sgr) * HD + d;
      ohi[oi] = hb;
      olo[oi] = lb;
    }
  }
}

// ----------------------------------------------------------- layernorm ----
__global__ __launch_bounds__(256) void k_layernorm(float* __restrict__ out,
                                                   const float* __restrict__ gamma,
                                                   const float* __restrict__ beta) {
  const int W = 2 * DIM;
  const int r = blockIdx.x;
  float* row = out + (size_t)r * W;
  const int t = threadIdx.x;
  float4 vals[2];
  float sum = 0.f, sq = 0.f;
#pragma unroll
  for (int i = 0; i < 2; ++i) {
    float4 v = *(const float4*)(row + (i * 256 + t) * 4);
    vals[i] = v;
    sum += v.x + v.y + v.z + v.w;
    sq += v.x * v.x + v.y * v.y + v.z * v.z + v.w * v.w;
  }
#pragma unroll
  for (int off = 32; off >= 1; off >>= 1) {
    sum += __shfl_xor(sum, off, 64);
    sq  += __shfl_xor(sq,  off, 64);
  }
  __shared__ float rs[4], rq[4];
  const int wave = t >> 6, lane = t & 63;
  if (lane == 0) { rs[wave] = sum; rq[wave] = sq; }
  __syncthreads();
  sum = rs[0] + rs[1] + rs[2] + rs[3];
  sq  = rq[0] + rq[1] + rq[2] + rq[3];
  const float mean = sum / W;
  const float var = sq / W - mean * mean;
  const float rstd = rsqrtf(var + 1e-5f);
#pragma unroll
  for (int i = 0; i < 2; ++i) {
    int base = (i * 256 + t) * 4;
    float4 v = vals[i];
    float4 g = *(const float4*)(gamma + base);
    float4 bb = *(const float4*)(beta + base);
    v.x = (v.x - mean) * rstd * g.x + bb.x;
    v.y = (v.y - mean) * rstd * g.y + bb.y;
    v.z = (v.z - mean) * rstd * g.z + bb.z;
    v.w = (v.w - mean) * rstd * g.w + bb.w;
    *(float4*)(row + base) = v;
  }
}

// ---------------------------------------------------------------- launch --
extern "C" void kernel_launch(void* const* d_in, const int* in_sizes, int n_in,
                              void* d_out, int out_size, void* d_ws, size_t ws_size,
                              hipStream_t stream) {
  const float* zr       = (const float*)d_in[0];
  const float* zi       = (const float*)d_in[1];
  const float* stored   = (const float*)d_in[3];
  const float* Wq       = (const float*)d_in[4];
  const float* Wk       = (const float*)d_in[5];
  const float* Wv       = (const float*)d_in[6];
  const float* Wo       = (const float*)d_in[7];
  const float* bo       = (const float*)d_in[8];
  const float* log_temp = (const float*)d_in[9];
  const float* gamma    = (const float*)d_in[10];
  const float* beta     = (const float*)d_in[11];
  float* out = (float*)d_out;

  // --- workspace layout, 64 MB peak with lifetime overlays ---
  char* base = (char*)d_ws;
  float* patt = (float*)(base + (size_t)0);                       // 0-12 MB
  unsigned short* vthi = (unsigned short*)(base + (size_t)0);     // 0-6  (over dead patt)
  unsigned short* vtlo = (unsigned short*)(base + (6u << 20));    // 6-12
  unsigned short* phi  = (unsigned short*)(base + (12u << 20));   // 12-18
  unsigned short* plo  = (unsigned short*)(base + (18u << 20));   // 18-24
  unsigned short* swhi = (unsigned short*)(base + (12u << 20));   // 12-16 (over dead phi/plo)
  unsigned short* swlo = (unsigned short*)(base + (16u << 20));   // 16-20
  unsigned short* wqh  = (unsigned short*)(base + (24u << 20));   // 24-26
  unsigned short* wql  = (unsigned short*)(base + (26u << 20));   // 26-28
  unsigned short* wkh  = (unsigned short*)(base + (28u << 20));   // 28-30
  unsigned short* wkl  = (unsigned short*)(base + (30u << 20));   // 30-32
  unsigned short* wvh  = (unsigned short*)(base + (32u << 20));   // 32-34
  unsigned short* wvl  = (unsigned short*)(base + (34u << 20));   // 34-36
  unsigned short* woh  = (unsigned short*)(base + (24u << 20));   // 24-28 (over dead wq/wk)
  unsigned short* wol  = (unsigned short*)(base + (28u << 20));   // 28-32
  float* mag = (float*)(base + (36u << 20));                      // 36-44
  unsigned short* qhi = (unsigned short*)(base + (36u << 20));    // 36-40 (over dead mag)
  unsigned short* qlo = (unsigned short*)(base + (40u << 20));    // 40-44
  unsigned short* s1hi = (unsigned short*)(base + (44u << 20));   // 44-48
  unsigned short* s1lo = (unsigned short*)(base + (48u << 20));   // 48-52
  unsigned short* khi  = (unsigned short*)(base + (52u << 20));   // 52-58
  unsigned short* klo  = (unsigned short*)(base + (58u << 20));   // 58-64

  const int n4 = B * S * DIM / 4;            // 524288
  k_mag<<<(n4 + 255) / 256, 256, 0, stream>>>(zr, zi, mag, n4);
  const int p4 = B * PT * DIM / 4;           // 786432
  k_patt<<<(p4 + 255) / 256, 256, 0, stream>>>(stored, mag, patt, p4);

  // splits: patterns + projection weights
  k_split_plain<<<p4 / 256, 256, 0, stream>>>(patt, phi, plo, p4);
  const int w4 = DIM * DIM / 4;              // 262144
  k_split_plain<<<w4 / 256, 256, 0, stream>>>(Wq, wqh, wql, w4);
  k_split_plain<<<w4 / 256, 256, 0, stream>>>(Wk, wkh, wkl, w4);
  k_split_plain<<<w4 / 256, 256, 0, stream>>>(Wv, wvh, wvl, w4);

  // Q = mag @ Wq^T  (A rows remapped into patt), head-major hi/lo out
  dim3 gq(1024 / 128, 2048 / 128);
  k_gemm_mfma<<<gq, 256, 0, stream>>>(phi, plo, wqh, wql, nullptr, nullptr,
                                      qhi, qlo, 2048, 1024, 1024, 1, 1024, 1);
  // K = patt @ Wk^T, head-major hi/lo out
  dim3 gkv(1024 / 128, 3072 / 128);
  k_gemm_mfma<<<gkv, 256, 0, stream>>>(phi, plo, wkh, wkl, nullptr, nullptr,
                                       khi, klo, 3072, 1024, 1024, 1, 1536, 0);
  // V = patt @ Wv^T, V^T hi/lo out
  k_gemm_mfma<<<gkv, 256, 0, stream>>>(phi, plo, wvh, wvl, nullptr, nullptr,
                                       vthi, vtlo, 3072, 1024, 1024, 2, 1536, 0);

  // Wo split (after wq/wk dead)
  const int wo4 = 2 * DIM * DIM / 4;         // 524288
  k_split_plain<<<wo4 / 256, 256, 0, stream>>>(Wo, woh, wol, wo4);

  const int ablocks = B * H * (S / 16);      // 2048
  k_attn_mfma<<<ablocks, 512, 0, stream>>>(qhi, qlo, khi, klo, vthi, vtlo,
                                           log_temp, swhi, swlo, s1hi, s1lo);
  k_attn_mfma<<<ablocks, 512, 0, stream>>>(s1hi, s1lo, khi, klo, vthi, vtlo,
                                           log_temp, swhi, swlo, qhi, qlo);
  k_attn_mfma<<<ablocks, 512, 0, stream>>>(qhi, qlo, khi, klo, vthi, vtlo,
                                           log_temp, swhi, swlo, s1hi, s1lo);

  // out = sw @ Wo^T + bo, fp32
  dim3 go(2048 / 128, 2048 / 128);
  k_gemm_mfma<<<go, 256, 0, stream>>>(swhi, swlo, woh, wol, bo, out,
                                      nullptr, nullptr, 2048, 2048, 1024, 0, 0, 0);
  k_layernorm<<<B * S, 256, 0, stream>>>(out, gamma, beta);
}